// Round 13
// baseline (194.301 us; speedup 1.0000x reference)
//
#include <hip/hip_runtime.h>

#define PI_F 3.14159265358979323846f

typedef short bf16x8 __attribute__((ext_vector_type(8)));
typedef float f32x4 __attribute__((ext_vector_type(4)));

#define MFMA16(acc, a, b) \
  acc = __builtin_amdgcn_mfma_f32_16x16x32_bf16(a, b, acc, 0, 0, 0)

// ---------------- workspace layout (float offsets) ----------------
#define WS_SPEC   0u          // (dead in v12: proj_in fused into k_fft, spec never hits global)
#define WS_H0     4194304u    // 32*32*128    [b][o][t]
#define WS_ACC    4325376u    // 32*128*32    [b][t][o]
#define WS_V      4456448u    // 32*32*128    [b][c][t]; ALSO: prep stashes the
                              // chain-weight bf16 packs in the first 16384 floats
#define WS_WTIN   4587520u    // legacy, unused
#define WS_WST    4620288u    // 32*256       [m][o2]
#define WS_WDT    4628480u    // 256*32       [o2][c]
#define WS_FRAMES 4636672u    // 32*32*2048   [c][f][j]
#define WS_RES    6733824u    // (dead: res assembly fused into obpack) -> Bh/Bl packs
// total 7782400 floats = ~29.7 MB

// ---- 2048-pt complex DIT FFT, bit-reversed input, 256 thr ----
// v9 structure (proven): radix-8 fusion, 4 LDS passes; BIX padding.
#define BIX(a) ((a) + ((a) >> 4))

#define BFLY(I0, I1, C, S)                                   \
  { float2 u = buf[I0]; float2 w = buf[I1];                  \
    float tr = (C) * w.x - (S) * w.y;                        \
    float ti = (C) * w.y + (S) * w.x;                        \
    buf[I0] = make_float2(u.x + tr, u.y + ti);               \
    buf[I1] = make_float2(u.x - tr, u.y - ti); }

#define CMULV(RX, RY, C, S, W) \
  { RX = (C) * (W).x - (S) * (W).y; RY = (C) * (W).y + (S) * (W).x; }

// fused stages (s, s+1): ws=(cs,ss) for stage s, w'=(cp,sp) for stage s+1.
__device__ __forceinline__ void quad_bfly(float2* buf, int a, int h,
                                          float cs, float ss, float cp, float sp) {
  float2 x0 = buf[BIX(a)],         x1 = buf[BIX(a + h)];
  float2 x2 = buf[BIX(a + 2 * h)], x3 = buf[BIX(a + 3 * h)];
  float t1x = cs * x1.x - ss * x1.y, t1y = cs * x1.y + ss * x1.x;
  float t3x = cs * x3.x - ss * x3.y, t3y = cs * x3.y + ss * x3.x;
  float2 y0 = make_float2(x0.x + t1x, x0.y + t1y);
  float2 y1 = make_float2(x0.x - t1x, x0.y - t1y);
  float2 y2 = make_float2(x2.x + t3x, x2.y + t3y);
  float2 y3 = make_float2(x2.x - t3x, x2.y - t3y);
  float u2x = cp * y2.x - sp * y2.y, u2y = cp * y2.y + sp * y2.x;
  float u3x = sp * y3.x + cp * y3.y, u3y = sp * y3.y - cp * y3.x;  // (-i w')*y3
  buf[BIX(a)]         = make_float2(y0.x + u2x, y0.y + u2y);
  buf[BIX(a + 2 * h)] = make_float2(y0.x - u2x, y0.y - u2y);
  buf[BIX(a + h)]     = make_float2(y1.x + u3x, y1.y + u3y);
  buf[BIX(a + 3 * h)] = make_float2(y1.x - u3x, y1.y - u3y);
}

// fused stages (s, s+1, s+2) on octet {a + k*h}, k=0..7. v = e^{-i pi j/4h}.
__device__ __forceinline__ void octet_bfly(float2* buf, int a, int h,
                                           float cv, float sv) {
  const float R = 0.7071067811865476f;
  float c1 = cv * cv - sv * sv, s1 = 2.f * cv * sv;   // w' = v^2
  float c2 = c1 * c1 - s1 * s1, s2 = 2.f * c1 * s1;   // ws = v^4
  float2 x0 = buf[BIX(a)],         x1 = buf[BIX(a + h)];
  float2 x2 = buf[BIX(a + 2 * h)], x3 = buf[BIX(a + 3 * h)];
  float2 x4 = buf[BIX(a + 4 * h)], x5 = buf[BIX(a + 5 * h)];
  float2 x6 = buf[BIX(a + 6 * h)], x7 = buf[BIX(a + 7 * h)];
  float tx, ty;
  CMULV(tx, ty, c2, s2, x1);
  float2 y0 = make_float2(x0.x + tx, x0.y + ty), y1 = make_float2(x0.x - tx, x0.y - ty);
  CMULV(tx, ty, c2, s2, x3);
  float2 y2 = make_float2(x2.x + tx, x2.y + ty), y3 = make_float2(x2.x - tx, x2.y - ty);
  CMULV(tx, ty, c2, s2, x5);
  float2 y4 = make_float2(x4.x + tx, x4.y + ty), y5 = make_float2(x4.x - tx, x4.y - ty);
  CMULV(tx, ty, c2, s2, x7);
  float2 y6 = make_float2(x6.x + tx, x6.y + ty), y7 = make_float2(x6.x - tx, x6.y - ty);
  CMULV(tx, ty, c1, s1, y2);
  float2 z0 = make_float2(y0.x + tx, y0.y + ty), z2 = make_float2(y0.x - tx, y0.y - ty);
  CMULV(tx, ty, c1, s1, y3);    // -i*u = (u.y, -u.x)
  float2 z1 = make_float2(y1.x + ty, y1.y - tx), z3 = make_float2(y1.x - ty, y1.y + tx);
  CMULV(tx, ty, c1, s1, y6);
  float2 z4 = make_float2(y4.x + tx, y4.y + ty), z6 = make_float2(y4.x - tx, y4.y - ty);
  CMULV(tx, ty, c1, s1, y7);
  float2 z5 = make_float2(y5.x + ty, y5.y - tx), z7 = make_float2(y5.x - ty, y5.y + tx);
  float ca = R * (cv + sv), sa = R * (sv - cv);   // v*w8
  float cb = sv,            sb = -cv;             // -i*v
  float cc = R * (sv - cv), sc = -R * (cv + sv);  // v*w8^3
  CMULV(tx, ty, cv, sv, z4);
  buf[BIX(a)]         = make_float2(z0.x + tx, z0.y + ty);
  buf[BIX(a + 4 * h)] = make_float2(z0.x - tx, z0.y - ty);
  CMULV(tx, ty, ca, sa, z5);
  buf[BIX(a + h)]     = make_float2(z1.x + tx, z1.y + ty);
  buf[BIX(a + 5 * h)] = make_float2(z1.x - tx, z1.y - ty);
  CMULV(tx, ty, cb, sb, z6);
  buf[BIX(a + 2 * h)] = make_float2(z2.x + tx, z2.y + ty);
  buf[BIX(a + 6 * h)] = make_float2(z2.x - tx, z2.y - ty);
  CMULV(tx, ty, cc, sc, z7);
  buf[BIX(a + 3 * h)] = make_float2(z3.x + tx, z3.y + ty);
  buf[BIX(a + 7 * h)] = make_float2(z3.x - tx, z3.y - ty);
}

__device__ __forceinline__ void fft2048_stages(float2* buf, int tid) {
  octet_bfly(buf, tid << 3, 1, 1.f, 0.f);
  __syncthreads();
  {
    int j = tid & 7;
    int a = ((tid >> 3) << 6) + j;
    float sv, cv;
    __sincosf(-PI_F / 32.f * (float)j, &sv, &cv);
    octet_bfly(buf, a, 8, cv, sv);
  }
  __syncthreads();
  {
    int j = tid & 63;
    int a = ((tid >> 6) << 9) + j;
    float sv, cv;
    __sincosf(-PI_F / 256.f * (float)j, &sv, &cv);
    octet_bfly(buf, a, 64, cv, sv);
  }
  __syncthreads();
  for (int g = tid; g < 512; g += 256) {
    float sp, cp;
    __sincosf(-PI_F / 1024.f * (float)g, &sp, &cp);   // w' (stage 10)
    float c2 = cp * cp - sp * sp, s2 = 2.f * cp * sp; // ws = w'^2 (stage 9)
    quad_bfly(buf, g, 512, c2, s2, cp, sp);
  }
  __syncthreads();
}

// ---------------- fused FFT kernel: STFT+proj_in | resonance | prep ----------------
// v12: proj_in fused into the STFT branch. After the FFT each block holds its 2
// frames' full 1024-bin spectrum in LDS -> compute magnitudes into registers,
// write back into buf (no extra LDS), then MAC against Win rows (float4 from
// L2, half-wave-broadcast ds_read_b64 from buf) and reduce to h0 directly.
// Eliminates the k_proj_in launch AND spec's 16MB write + 16MB read. Same
// thread partition (o=tid&31, p=tid>>5, k ascending, p2 ascending reduce) as
// the v9 proj -> FP ordering matches within rounding.
__global__ __launch_bounds__(256) void k_fft(const float* __restrict__ audio,
                                             const float* __restrict__ resin,
                                             const float* __restrict__ Win,
                                             const float* __restrict__ Ws,
                                             const float* __restrict__ Wd,
                                             const float* __restrict__ bwIn,
                                             const float* __restrict__ bin,
                                             float* __restrict__ h0,
                                             float* __restrict__ frames,
                                             float* __restrict__ WsT,
                                             float* __restrict__ WdT,
                                             short* __restrict__ Whg,
                                             short* __restrict__ Wlg) {
  __shared__ float2 buf[2176];        // 2048 + BIX padding
  __shared__ float red[512];          // [o][frame][p] for the fused proj
  int blk = blockIdx.x;

  if (blk >= 2560) {                  // ---- prep branch (no LDS use, no syncs) ----
    int i = (blk - 2560) * 256 + threadIdx.x;
    if (i < 8192)  { int o2 = i >> 5, m = i & 31;   WsT[m * 256 + o2] = Ws[i]; }
    if (i < 8192)  { int c = i >> 8, o2 = i & 255;  WdT[o2 * 32 + c] = Wd[i]; }
    if (i < 16384) {
      // i = ((s*32+o)*32+m)*2 + w
      int w = i & 1, m = (i >> 1) & 31, o = (i >> 6) & 31, s = i >> 11;
      float val = bwIn[i];
      unsigned bits = __float_as_uint(val);
      float rem = val - __uint_as_float(bits & 0xffff0000u);
      int row = (s * 2 + w) * 32 + o;
      Whg[row * 32 + m] = (short)(bits >> 16);
      Wlg[row * 32 + m] = (short)(__float_as_uint(rem) >> 16);
    }
    return;
  }

  if (blk < 2048) {
    int b  = blk >> 6;
    int f0 = (blk & 63) * 2;      // frames f0, f0+1
    for (int j = threadIdx.x; j < 2048; j += 256) {
      float h = 0.5f - 0.5f * __cosf(0.0030679615757712823f * (float)j); // 2pi/2048
      int i1 = f0 * 256 + j;
      int i2 = i1 + 256;
      float a1 = (i1 < 32768) ? audio[b * 32768 + i1] : 0.f;
      float a2 = (i2 < 32768) ? audio[b * 32768 + i2] : 0.f;
      buf[BIX(__brev((unsigned)j) >> 21)] = make_float2(a1 * h, a2 * h);
    }
    __syncthreads();
    fft2048_stages(buf, threadIdx.x);
    // magnitudes (Hermitian unpack) into registers
    const float scale = 0.5f * 0.022097086912079608f;  // 0.5 / sqrt(2048)
    float m1r[4], m2r[4];
#pragma unroll
    for (int q = 0; q < 4; ++q) {
      int k = threadIdx.x + q * 256;
      float2 zk = buf[BIX(k)];
      float2 zn = buf[BIX((2048 - k) & 2047)];
      float f1r = zk.x + zn.x, f1i = zk.y - zn.y;
      float f2r = zk.y + zn.y, f2i = zk.x - zn.x;
      m1r[q] = sqrtf(f1r * f1r + f1i * f1i) * scale;
      m2r[q] = sqrtf(f2r * f2r + f2i * f2i) * scale;
    }
    __syncthreads();                 // all Hermitian reads done before overwrite
#pragma unroll
    for (int q = 0; q < 4; ++q) {
      int k = threadIdx.x + q * 256;
      buf[BIX(k)] = make_float2(m1r[q], m2r[q]);
    }
    __syncthreads();
    // fused proj_in: h0[b][o][f0+f] = bias[o] + sum_k Win[o][k]*mag_f[k]
    int o = threadIdx.x & 31, p = threadIdx.x >> 5;
    float part1 = 0.f, part2 = 0.f;
    const float4* Wrow = (const float4*)(Win + o * 1024);   // Win is [o][k]
    for (int k4 = p * 32; k4 < p * 32 + 32; ++k4) {
      float4 w4 = Wrow[k4];
      int k = k4 * 4;
      float2 s0 = buf[BIX(k)],     s1 = buf[BIX(k + 1)];
      float2 s2 = buf[BIX(k + 2)], s3 = buf[BIX(k + 3)];
      part1 += w4.x * s0.x + w4.y * s1.x + w4.z * s2.x + w4.w * s3.x;
      part2 += w4.x * s0.y + w4.y * s1.y + w4.z * s2.y + w4.w * s3.y;
    }
    red[(o * 2 + 0) * 8 + p] = part1;
    red[(o * 2 + 1) * 8 + p] = part2;
    __syncthreads();
    if (threadIdx.x < 64) {
      int oo = threadIdx.x >> 1, ff = threadIdx.x & 1;
      float s = bin[oo];
#pragma unroll
      for (int p2 = 0; p2 < 8; ++p2) s += red[(oo * 2 + ff) * 8 + p2];
      h0[b * 4096 + oo * 128 + f0 + ff] = s;
    }
  } else {
    int r = blk - 2048;           // 0..511
    int c = r >> 4;
    int g = r & 15;               // frames 2g (exp 2g+1), 2g+1 (exp 2g+2)
    float e1 = (float)(2 * g + 1);
    for (int k = threadIdx.x; k < 2048; k += 256) {
      int kk = (k <= 1024) ? k : 2048 - k;   // Hermitian (real) extension
      float cv = resin[c * 1025 + kk];
      cv = fminf(fmaxf(cv, 0.f), 0.9999f);
      float m1 = __powf(cv, e1);
      float m2 = m1 * cv;
      buf[BIX(__brev((unsigned)k) >> 21)] = make_float2(m1, m2);
    }
    __syncthreads();
    fft2048_stages(buf, threadIdx.x);
    for (int j = threadIdx.x; j < 2048; j += 256) {
      float h  = 0.5f - 0.5f * __cosf(0.0030679615757712823f * (float)j);
      float sc = h * (1.f / 2048.f);
      float2 z = buf[BIX(j)];
      frames[(c * 32 + 2 * g) * 2048 + j]     = z.x * sc;
      frames[(c * 32 + 2 * g + 1) * 2048 + j] = z.y * sc;
    }
  }
}

// ---------------- chain (blocks 0..31) + fused overlap-add/B-pack (blocks 32..159) ----------------
__global__ __launch_bounds__(1024) void k_chain(const float* __restrict__ h0,
                                                const short* __restrict__ Whg,
                                                const short* __restrict__ Wlg,
                                                const float* __restrict__ bb,
                                                float* __restrict__ accout,
                                                const float* __restrict__ frames,
                                                short* __restrict__ Bh,
                                                short* __restrict__ Bl) {
  __shared__ __align__(16) short Hh[192 * 40];   // rows stride 40 bf16 (80 B)
  __shared__ __align__(16) short Hl[192 * 40];
  __shared__ float Hf[128 * 33];                 // fp32 H for exact residual
  __shared__ float bL[256];
  __shared__ float red[16];
  int blk = blockIdx.x, tid = threadIdx.x;

  if (blk >= 32) {                  // ---- obpack branch (no LDS use, no syncs) ----
    int ubb = (blk - 32) * 4 + (tid >> 8);   // old obpack block id 0..511
    int r   = tid & 255;
    int c   = ubb >> 4, o = ubb & 15;
    bf16x8 hv, lv;
#pragma unroll
    for (int j = 0; j < 8; ++j) {
      int fo = 8 * o + j;
      int g  = fo >> 2;
      int j0 = ((fo & 3) << 8) + r;
      float val = frames[(c * 32 + g) * 2048 + j0];
      if (g > 0) val += frames[(c * 32 + g - 1) * 2048 + j0 + 1024];
      unsigned bits = __float_as_uint(val);
      float rem = val - __uint_as_float(bits & 0xffff0000u);
      hv[j] = (short)(bits >> 16);
      lv[j] = (short)(__float_as_uint(rem) >> 16);
    }
    int unit = (ubb * 16 + (r >> 4)) * 16 + (r & 15);
    ((bf16x8*)Bh)[unit] = hv;
    ((bf16x8*)Bl)[unit] = lv;
    return;
  }

  int b = blk;
  for (int i = tid; i < 4096; i += 1024) {
    int t = i & 127;                 // h0 layout [o][t]
    int o = i >> 7;
    float val = h0[b * 4096 + i];
    Hf[t * 33 + o] = val;
    unsigned bits = __float_as_uint(val);
    float rem = val - __uint_as_float(bits & 0xffff0000u);
    Hh[t * 40 + o] = (short)(bits >> 16);
    Hl[t * 40 + o] = (short)(__float_as_uint(rem) >> 16);
  }
  for (int i = tid; i < 64 * 40; i += 1024) {    // zero pad rows 128..191
    Hh[128 * 40 + i] = 0;
    Hl[128 * 40 + i] = 0;
  }
  if (tid < 256) bL[tid] = bb[tid];
  __syncthreads();

  int wave = tid >> 6, lane = tid & 63;
  int quad = lane >> 4, l15 = lane & 15;
  int t0 = (wave & 7) * 16, o0 = (wave >> 3) * 16;
  int tD = t0 + quad * 4;          // D rows tD..tD+3
  int oD = o0 + l15;               // D col

  const bf16x8* Hh8 = (const bf16x8*)Hh;   // unit = row*5 + quad (40 bf16 = 5 units)
  const bf16x8* Hl8 = (const bf16x8*)Hl;
  const bf16x8* Wh8 = (const bf16x8*)Whg;  // unit = row*4 + quad (32 bf16 = 4 units)
  const bf16x8* Wl8 = (const bf16x8*)Wlg;

  float accsum[4] = {0.f, 0.f, 0.f, 0.f};
  const int DIL[8] = {1, 2, 4, 8, 16, 32, 64, 1};

#pragma unroll
  for (int s = 0; s < 8; ++s) {
    int arow = t0 + l15;
    int frow = arow + DIL[s];        // <= 191, pad rows give zeros
    bf16x8 Ah = Hh8[arow * 5 + quad];
    bf16x8 Al = Hl8[arow * 5 + quad];
    bf16x8 Fh = Hh8[frow * 5 + quad];
    bf16x8 Fl = Hl8[frow * 5 + quad];
    int w0row = ((s * 2 + 0) * 32 + oD) * 4 + quad;
    int w1row = ((s * 2 + 1) * 32 + oD) * 4 + quad;
    bf16x8 B0h = Wh8[w0row], B0l = Wl8[w0row];
    bf16x8 B1h = Wh8[w1row], B1l = Wl8[w1row];
    float bias = bL[s * 32 + oD];
    f32x4 acc = {bias, bias, bias, bias};
    MFMA16(acc, Ah, B0h); MFMA16(acc, Ah, B0l); MFMA16(acc, Al, B0h);
    MFMA16(acc, Fh, B1h); MFMA16(acc, Fh, B1l); MFMA16(acc, Fl, B1h);
    float hnew[4], lmax = 0.f;
#pragma unroll
    for (int r = 0; r < 4; ++r) {
      float sv = acc[r];
      sv = (sv > 0.f) ? sv : 0.2f * sv;       // leaky_relu 0.2
      sv += Hf[(tD + r) * 33 + oD];           // residual (exact fp32)
      hnew[r] = sv;
      lmax = fmaxf(lmax, fabsf(sv));
    }
#pragma unroll
    for (int off = 32; off > 0; off >>= 1)
      lmax = fmaxf(lmax, __shfl_down(lmax, off, 64));
    if (lane == 0) red[wave] = lmax;
    __syncthreads();                 // red visible; all H reads of this step done
    float mx = red[0];
#pragma unroll
    for (int i = 1; i < 16; ++i) mx = fmaxf(mx, red[i]);
    float nm = 1.f / (mx + 1e-8f);
#pragma unroll
    for (int r = 0; r < 4; ++r) {
      float hv = hnew[r] * nm;
      accsum[r] += hv;
      int t = tD + r;
      Hf[t * 33 + oD] = hv;
      unsigned bits = __float_as_uint(hv);
      float rem = hv - __uint_as_float(bits & 0xffff0000u);
      Hh[t * 40 + oD] = (short)(bits >> 16);
      Hl[t * 40 + oD] = (short)(__float_as_uint(rem) >> 16);
    }
    __syncthreads();                 // new H visible for next step
  }
#pragma unroll
  for (int r = 0; r < 4; ++r)
    accout[b * 4096 + (tD + r) * 32 + oD] = accsum[r];
}

// ---------------- sparse + dense, 8 t per block ----------------
__global__ __launch_bounds__(256) void k_sparse_dense(const float* __restrict__ acc,
                                                      const float* __restrict__ WsT,
                                                      const float* __restrict__ bs,
                                                      const float* __restrict__ WdT,
                                                      const float* __restrict__ bd,
                                                      float* __restrict__ out_sparse,
                                                      float* __restrict__ v) {
  __shared__ float accL[8][32];
  __shared__ float sL[8][256];
  __shared__ float red[8][8][32];   // [p][tt][c]
  int b = blockIdx.x >> 4, tq = blockIdx.x & 15;
  int t0 = tq * 8;
  int tid = threadIdx.x;
  accL[tid >> 5][tid & 31] = acc[b * 4096 + (t0 + (tid >> 5)) * 32 + (tid & 31)];
  __syncthreads();
  float bsv = bs[tid];
  float s[8];
#pragma unroll
  for (int j = 0; j < 8; ++j) s[j] = bsv;
  for (int m = 0; m < 32; ++m) {
    float w = WsT[m * 256 + tid];
#pragma unroll
    for (int j = 0; j < 8; ++j) s[j] += w * accL[j][m];
  }
  float* os = out_sparse + b * 32768 + tid * 128 + t0;
#pragma unroll
  for (int j = 0; j < 8; ++j) {
    s[j] = fmaxf(s[j], 0.f);
    os[j] = s[j];
    sL[j][tid] = s[j];
  }
  __syncthreads();
  int c = tid & 31, p = tid >> 5;
  float pp[8] = {0.f,0.f,0.f,0.f,0.f,0.f,0.f,0.f};
  for (int jj = 0; jj < 32; ++jj) {
    int o2 = p * 32 + jj;
    float w = WdT[o2 * 32 + c];
#pragma unroll
    for (int j = 0; j < 8; ++j) pp[j] += w * sL[j][o2];
  }
#pragma unroll
  for (int j = 0; j < 8; ++j) red[p][j][c] = pp[j];
  __syncthreads();
  {
    int tt = tid >> 5, cc = tid & 31;
    float vv = bd[cc];
#pragma unroll
    for (int p2i = 0; p2i < 8; ++p2i) vv += red[p2i][tt][cc];
    v[b * 4096 + cc * 128 + t0 + tt] = vv;
  }
}

// ---------------- final conv as MFMA GEMM, v11 (proven): two-phase + B prefetch ----------------
// v4 structure (two-phase, 40 KB LDS) + 1-step-ahead B prefetch across the
// flattened 16-step loop. VGPR ~104 -> 4 waves/SIMD cap (m69 boundary at 128);
// do NOT deepen prefetch (would cross 128-VGPR cliff and halve occupancy).
// XCD-group swizzle: all 32 b-blocks of one (j,uc) share one XCD's L2 slice.
__global__ __launch_bounds__(512, 4) void k_conv(const float* __restrict__ v,
                                                 const short* __restrict__ Bh,
                                                 const short* __restrict__ Bl,
                                                 float* __restrict__ y) {
  __shared__ __align__(16) short AH[32 * 264];   // [row 32][K 256 + pad 8]
  __shared__ __align__(16) short AL[32 * 264];
  __shared__ float vwin[2][16][48];              // [c-half][c_local][ii]

  // --- XCD-group swizzle: group e (20 of them) -> XCD e%8; batches fill slots.
  int xcd  = blockIdx.x & 7;
  int slot = blockIdx.x >> 3;
  int e, b;
  if      (slot < 32) { e = xcd;      b = slot; }
  else if (slot < 64) { e = xcd + 8;  b = slot - 32; }
  else                { e = (xcd < 4) ? (xcd + 16) : (xcd + 12);
                        b = (xcd < 4) ? (slot - 64) : (slot - 48); }
  int j, uc;
  if      (e < 2)  { j = 0; uc = e; }
  else if (e < 6)  { j = 1; uc = e - 2; }
  else if (e < 12) { j = 2; uc = e - 6; }
  else             { j = 3; uc = e - 12; }
  int D0 = 32 * j - 16 * uc;       // d = D0 - 15 + ii, ii in [0,46]

  // stage compact v windows (both c-halves): 2*16*47 floats
  for (int i = threadIdx.x; i < 1504; i += 512) {
    int ii = i % 47;
    int r  = i / 47;               // 0..31
    int c  = r & 15, ph = r >> 4;
    int d  = D0 - 15 + ii;
    vwin[ph][c][ii] = (d >= 0 && d < 128)
        ? v[b * 4096 + (16 * ph + c) * 128 + d] : 0.f;
  }
  __syncthreads();

  int lane = threadIdx.x & 63, wave = threadIdx.x >> 6;
  int quad = lane >> 4, l15 = lane & 15;
  int cq   = quad >> 1;            // low bit of c
  int og   = 2 * uc + (quad & 1);  // global u-octet
  int nt0  = wave * 2;             // 8 waves x 2 nt = 16 nt

  f32x4 acc00 = (f32x4)0.f, acc01 = (f32x4)0.f;   // [qs][t]
  f32x4 acc10 = (f32x4)0.f, acc11 = (f32x4)0.f;

  const bf16x8* AH8 = (const bf16x8*)AH;
  const bf16x8* AL8 = (const bf16x8*)AL;
  const bf16x8* Bh8 = (const bf16x8*)Bh;
  const bf16x8* Bl8 = (const bf16x8*)Bl;
  short2* AH2 = (short2*)AH;
  short2* AL2 = (short2*)AL;

  int abase0 = (0 * 16 + l15) * 33 + quad;   // bf16x8 units, row stride 33
  int abase1 = (1 * 16 + l15) * 33 + quad;

  // prefetch B for step 0 (p=0, ks=0 -> c = cq)
  bf16x8 pbh0, pbl0, pbh1, pbl1;
  {
    int bb0 = (cq * 16 + og) * 256 + l15;
    pbh0 = Bh8[bb0 + nt0 * 16];       pbl0 = Bl8[bb0 + nt0 * 16];
    pbh1 = Bh8[bb0 + (nt0 + 1) * 16]; pbl1 = Bl8[bb0 + (nt0 + 1) * 16];
  }

#pragma unroll
  for (int p = 0; p < 2; ++p) {
    // expand Toeplitz A (hi/lo split) for this c-half: 32 rows x 128 kk-pairs
    for (int i = threadIdx.x; i < 4096; i += 512) {
      int kk2 = i & 127;           // kk = 2*kk2 (pair shares c_local)
      int row = i >> 7;            // 0..31
      int cl  = kk2 >> 3;
      int uu  = (kk2 & 7) * 2;
      int ii  = row - uu + 15;
      float v0 = vwin[p][cl][ii];
      float v1 = vwin[p][cl][ii - 1];
      unsigned w0 = __float_as_uint(v0), w1 = __float_as_uint(v1);
      float r0 = v0 - __uint_as_float(w0 & 0xffff0000u);
      float r1 = v1 - __uint_as_float(w1 & 0xffff0000u);
      int u2 = row * 132 + kk2;    // short2 units, row stride 132
      AH2[u2] = make_short2((short)(w0 >> 16), (short)(w1 >> 16));
      AL2[u2] = make_short2((short)(__float_as_uint(r0) >> 16),
                            (short)(__float_as_uint(r1) >> 16));
    }
    __syncthreads();

#pragma unroll
    for (int ks = 0; ks < 8; ++ks) {
      // consume prefetched B for this step
      bf16x8 bh0 = pbh0, bl0 = pbl0, bh1 = pbh1, bl1 = pbl1;
      // issue prefetch for next step (crosses the phase barrier for p0->p1)
      int step = p * 8 + ks + 1;
      if (step < 16) {
        int cn  = 16 * (step >> 3) + 2 * (step & 7) + cq;
        int bbn = (cn * 16 + og) * 256 + l15;
        pbh0 = Bh8[bbn + nt0 * 16];       pbl0 = Bl8[bbn + nt0 * 16];
        pbh1 = Bh8[bbn + (nt0 + 1) * 16]; pbl1 = Bl8[bbn + (nt0 + 1) * 16];
      }
      bf16x8 ah0 = AH8[abase0 + ks * 4];
      bf16x8 al0 = AL8[abase0 + ks * 4];
      bf16x8 ah1 = AH8[abase1 + ks * 4];
      bf16x8 al1 = AL8[abase1 + ks * 4];
      MFMA16(acc00, ah0, bh0); MFMA16(acc00, ah0, bl0); MFMA16(acc00, al0, bh0);
      MFMA16(acc10, ah1, bh0); MFMA16(acc10, ah1, bl0); MFMA16(acc10, al1, bh0);
      MFMA16(acc01, ah0, bh1); MFMA16(acc01, ah0, bl1); MFMA16(acc01, al0, bh1);
      MFMA16(acc11, ah1, bh1); MFMA16(acc11, ah1, bl1); MFMA16(acc11, al1, bh1);
    }
    __syncthreads();               // A consumed; safe to overwrite in next phase
  }

  {
    float* yb0 = y + b * 32768 + (32 * j + 0 * 16 + quad * 4) * 256 + l15;
    float* yb1 = y + b * 32768 + (32 * j + 1 * 16 + quad * 4) * 256 + l15;
#pragma unroll
    for (int reg = 0; reg < 4; ++reg) {
      atomicAdd(yb0 + reg * 256 + (nt0 + 0) * 16, acc00[reg]);
      atomicAdd(yb0 + reg * 256 + (nt0 + 1) * 16, acc01[reg]);
      atomicAdd(yb1 + reg * 256 + (nt0 + 0) * 16, acc10[reg]);
      atomicAdd(yb1 + reg * 256 + (nt0 + 1) * 16, acc11[reg]);
    }
  }
}

extern "C" void kernel_launch(void* const* d_in, const int* in_sizes, int n_in,
                              void* d_out, int out_size, void* d_ws, size_t ws_size,
                              hipStream_t stream) {
  const float* audio = (const float*)d_in[0];
  const float* Win   = (const float*)d_in[1];
  const float* bin   = (const float*)d_in[2];
  const float* bw    = (const float*)d_in[3];
  const float* bb    = (const float*)d_in[4];
  const float* Ws    = (const float*)d_in[5];
  const float* bs    = (const float*)d_in[6];
  const float* Wd    = (const float*)d_in[7];
  const float* bd    = (const float*)d_in[8];
  const float* reson = (const float*)d_in[9];

  float* out = (float*)d_out;           // [0,1048576) = y ; [1048576,2097152) = sparse
  float* ws  = (float*)d_ws;

  float* h0     = ws + WS_H0;
  float* accb   = ws + WS_ACC;
  float* vbuf   = ws + WS_V;
  float* WsT    = ws + WS_WST;
  float* WdT    = ws + WS_WDT;
  float* frames = ws + WS_FRAMES;
  // WS_RES region (dead after fusing overlap-add into chain launch) -> bf16 B packs
  short* Bh = (short*)(ws + WS_RES);               // 1,048,576 bf16 = 2 MB
  short* Bl = (short*)(ws + WS_RES + 524288u);     // 1,048,576 bf16 = 2 MB
  // chain-weight packs live in WS_V until k_sparse_dense overwrites it (after k_chain)
  short* Whg = (short*)(ws + WS_V);                // 16384 bf16 = 32 KB
  short* Wlg = (short*)(ws + WS_V + 8192u);        // 16384 bf16 = 32 KB

  // zero y region (atomicAdd target); d_out is poisoned before every launch
  hipMemsetAsync(d_out, 0, 1048576u * sizeof(float), stream);

  k_fft<<<2688, 256, 0, stream>>>(audio, reson, Win, Ws, Wd, bw, bin,
                                  h0, frames, WsT, WdT, Whg, Wlg);
  k_chain<<<160, 1024, 0, stream>>>(h0, Whg, Wlg, bb, accb, frames, Bh, Bl);
  k_sparse_dense<<<512, 256, 0, stream>>>(accb, WsT, bs, WdT, bd, out + 1048576, vbuf);
  k_conv<<<640, 512, 0, stream>>>(vbuf, Bh, Bl, out);
}

// Round 14
// 173.700 us; speedup vs baseline: 1.1186x; 1.1186x over previous
//
#include <hip/hip_runtime.h>

#define PI_F 3.14159265358979323846f

typedef short bf16x8 __attribute__((ext_vector_type(8)));
typedef float f32x4 __attribute__((ext_vector_type(4)));

#define MFMA16(acc, a, b) \
  acc = __builtin_amdgcn_mfma_f32_16x16x32_bf16(a, b, acc, 0, 0, 0)

// ---------------- workspace layout (float offsets) ----------------
#define WS_SPEC   0u          // 32*128*1024  [b][t][k]
#define WS_H0     4194304u    // 32*32*128    [b][o][t]
#define WS_ACC    4325376u    // 32*128*32    [b][t][o]
#define WS_V      4456448u    // 32*32*128    [b][c][t]; ALSO: prep stashes the
                              // chain-weight bf16 packs in the first 16384 floats
#define WS_WTIN   4587520u    // legacy, unused
#define WS_WST    4620288u    // 32*256       [m][o2]
#define WS_WDT    4628480u    // 256*32       [o2][c]
#define WS_FRAMES 4636672u    // 32*32*2048   [c][f][j]
#define WS_RES    6733824u    // (dead: res assembly fused into obpack) -> Bh/Bl packs
// total 7782400 floats = ~29.7 MB

// ---- 2048-pt complex DIT FFT, bit-reversed input, 256 thr ----
// v9 structure (proven): radix-8 fusion, 4 LDS passes; BIX padding.
// v13 note: v12's fused proj_in was REVERTED -- it forced a 28-VGPR allocation
// (octet registers spilled to scratch; whole kernel 2.5x slower) and cut the
// Win amortization from 8 frames/block to 2 (4x transaction count). proj_in
// stays a separate 512-block launch with 8-frame Win reuse.
#define BIX(a) ((a) + ((a) >> 4))

#define BFLY(I0, I1, C, S)                                   \
  { float2 u = buf[I0]; float2 w = buf[I1];                  \
    float tr = (C) * w.x - (S) * w.y;                        \
    float ti = (C) * w.y + (S) * w.x;                        \
    buf[I0] = make_float2(u.x + tr, u.y + ti);               \
    buf[I1] = make_float2(u.x - tr, u.y - ti); }

#define CMULV(RX, RY, C, S, W) \
  { RX = (C) * (W).x - (S) * (W).y; RY = (C) * (W).y + (S) * (W).x; }

// fused stages (s, s+1): ws=(cs,ss) for stage s, w'=(cp,sp) for stage s+1.
__device__ __forceinline__ void quad_bfly(float2* buf, int a, int h,
                                          float cs, float ss, float cp, float sp) {
  float2 x0 = buf[BIX(a)],         x1 = buf[BIX(a + h)];
  float2 x2 = buf[BIX(a + 2 * h)], x3 = buf[BIX(a + 3 * h)];
  float t1x = cs * x1.x - ss * x1.y, t1y = cs * x1.y + ss * x1.x;
  float t3x = cs * x3.x - ss * x3.y, t3y = cs * x3.y + ss * x3.x;
  float2 y0 = make_float2(x0.x + t1x, x0.y + t1y);
  float2 y1 = make_float2(x0.x - t1x, x0.y - t1y);
  float2 y2 = make_float2(x2.x + t3x, x2.y + t3y);
  float2 y3 = make_float2(x2.x - t3x, x2.y - t3y);
  float u2x = cp * y2.x - sp * y2.y, u2y = cp * y2.y + sp * y2.x;
  float u3x = sp * y3.x + cp * y3.y, u3y = sp * y3.y - cp * y3.x;  // (-i w')*y3
  buf[BIX(a)]         = make_float2(y0.x + u2x, y0.y + u2y);
  buf[BIX(a + 2 * h)] = make_float2(y0.x - u2x, y0.y - u2y);
  buf[BIX(a + h)]     = make_float2(y1.x + u3x, y1.y + u3y);
  buf[BIX(a + 3 * h)] = make_float2(y1.x - u3x, y1.y - u3y);
}

// fused stages (s, s+1, s+2) on octet {a + k*h}, k=0..7. v = e^{-i pi j/4h}.
__device__ __forceinline__ void octet_bfly(float2* buf, int a, int h,
                                           float cv, float sv) {
  const float R = 0.7071067811865476f;
  float c1 = cv * cv - sv * sv, s1 = 2.f * cv * sv;   // w' = v^2
  float c2 = c1 * c1 - s1 * s1, s2 = 2.f * c1 * s1;   // ws = v^4
  float2 x0 = buf[BIX(a)],         x1 = buf[BIX(a + h)];
  float2 x2 = buf[BIX(a + 2 * h)], x3 = buf[BIX(a + 3 * h)];
  float2 x4 = buf[BIX(a + 4 * h)], x5 = buf[BIX(a + 5 * h)];
  float2 x6 = buf[BIX(a + 6 * h)], x7 = buf[BIX(a + 7 * h)];
  float tx, ty;
  CMULV(tx, ty, c2, s2, x1);
  float2 y0 = make_float2(x0.x + tx, x0.y + ty), y1 = make_float2(x0.x - tx, x0.y - ty);
  CMULV(tx, ty, c2, s2, x3);
  float2 y2 = make_float2(x2.x + tx, x2.y + ty), y3 = make_float2(x2.x - tx, x2.y - ty);
  CMULV(tx, ty, c2, s2, x5);
  float2 y4 = make_float2(x4.x + tx, x4.y + ty), y5 = make_float2(x4.x - tx, x4.y - ty);
  CMULV(tx, ty, c2, s2, x7);
  float2 y6 = make_float2(x6.x + tx, x6.y + ty), y7 = make_float2(x6.x - tx, x6.y - ty);
  CMULV(tx, ty, c1, s1, y2);
  float2 z0 = make_float2(y0.x + tx, y0.y + ty), z2 = make_float2(y0.x - tx, y0.y - ty);
  CMULV(tx, ty, c1, s1, y3);    // -i*u = (u.y, -u.x)
  float2 z1 = make_float2(y1.x + ty, y1.y - tx), z3 = make_float2(y1.x - ty, y1.y + tx);
  CMULV(tx, ty, c1, s1, y6);
  float2 z4 = make_float2(y4.x + tx, y4.y + ty), z6 = make_float2(y4.x - tx, y4.y - ty);
  CMULV(tx, ty, c1, s1, y7);
  float2 z5 = make_float2(y5.x + ty, y5.y - tx), z7 = make_float2(y5.x - ty, y5.y + tx);
  float ca = R * (cv + sv), sa = R * (sv - cv);   // v*w8
  float cb = sv,            sb = -cv;             // -i*v
  float cc = R * (sv - cv), sc = -R * (cv + sv);  // v*w8^3
  CMULV(tx, ty, cv, sv, z4);
  buf[BIX(a)]         = make_float2(z0.x + tx, z0.y + ty);
  buf[BIX(a + 4 * h)] = make_float2(z0.x - tx, z0.y - ty);
  CMULV(tx, ty, ca, sa, z5);
  buf[BIX(a + h)]     = make_float2(z1.x + tx, z1.y + ty);
  buf[BIX(a + 5 * h)] = make_float2(z1.x - tx, z1.y - ty);
  CMULV(tx, ty, cb, sb, z6);
  buf[BIX(a + 2 * h)] = make_float2(z2.x + tx, z2.y + ty);
  buf[BIX(a + 6 * h)] = make_float2(z2.x - tx, z2.y - ty);
  CMULV(tx, ty, cc, sc, z7);
  buf[BIX(a + 3 * h)] = make_float2(z3.x + tx, z3.y + ty);
  buf[BIX(a + 7 * h)] = make_float2(z3.x - tx, z3.y - ty);
}

__device__ __forceinline__ void fft2048_stages(float2* buf, int tid) {
  octet_bfly(buf, tid << 3, 1, 1.f, 0.f);
  __syncthreads();
  {
    int j = tid & 7;
    int a = ((tid >> 3) << 6) + j;
    float sv, cv;
    __sincosf(-PI_F / 32.f * (float)j, &sv, &cv);
    octet_bfly(buf, a, 8, cv, sv);
  }
  __syncthreads();
  {
    int j = tid & 63;
    int a = ((tid >> 6) << 9) + j;
    float sv, cv;
    __sincosf(-PI_F / 256.f * (float)j, &sv, &cv);
    octet_bfly(buf, a, 64, cv, sv);
  }
  __syncthreads();
  for (int g = tid; g < 512; g += 256) {
    float sp, cp;
    __sincosf(-PI_F / 1024.f * (float)g, &sp, &cp);   // w' (stage 10)
    float c2 = cp * cp - sp * sp, s2 = 2.f * cp * sp; // ws = w'^2 (stage 9)
    quad_bfly(buf, g, 512, c2, s2, cp, sp);
  }
  __syncthreads();
}

// ---------------- fused FFT kernel: STFT pairs + resonance pairs + prep tail ----------------
__global__ __launch_bounds__(256) void k_fft(const float* __restrict__ audio,
                                             const float* __restrict__ resin,
                                             const float* __restrict__ Win,
                                             const float* __restrict__ Ws,
                                             const float* __restrict__ Wd,
                                             const float* __restrict__ bwIn,
                                             float* __restrict__ spec,
                                             float* __restrict__ frames,
                                             float* __restrict__ WsT,
                                             float* __restrict__ WdT,
                                             short* __restrict__ Whg,
                                             short* __restrict__ Wlg) {
  __shared__ float2 buf[2176];        // 2048 + BIX padding
  int blk = blockIdx.x;

  if (blk >= 2560) {                  // ---- prep branch (no LDS use, no syncs) ----
    int i = (blk - 2560) * 256 + threadIdx.x;
    if (i < 8192)  { int o2 = i >> 5, m = i & 31;   WsT[m * 256 + o2] = Ws[i]; }
    if (i < 8192)  { int c = i >> 8, o2 = i & 255;  WdT[o2 * 32 + c] = Wd[i]; }
    if (i < 16384) {
      // i = ((s*32+o)*32+m)*2 + w
      int w = i & 1, m = (i >> 1) & 31, o = (i >> 6) & 31, s = i >> 11;
      float val = bwIn[i];
      unsigned bits = __float_as_uint(val);
      float rem = val - __uint_as_float(bits & 0xffff0000u);
      int row = (s * 2 + w) * 32 + o;
      Whg[row * 32 + m] = (short)(bits >> 16);
      Wlg[row * 32 + m] = (short)(__float_as_uint(rem) >> 16);
    }
    return;
  }

  if (blk < 2048) {
    int b  = blk >> 6;
    int f0 = (blk & 63) * 2;      // frames f0, f0+1
    for (int j = threadIdx.x; j < 2048; j += 256) {
      float h = 0.5f - 0.5f * __cosf(0.0030679615757712823f * (float)j); // 2pi/2048
      int i1 = f0 * 256 + j;
      int i2 = i1 + 256;
      float a1 = (i1 < 32768) ? audio[b * 32768 + i1] : 0.f;
      float a2 = (i2 < 32768) ? audio[b * 32768 + i2] : 0.f;
      buf[BIX(__brev((unsigned)j) >> 21)] = make_float2(a1 * h, a2 * h);
    }
    __syncthreads();
    fft2048_stages(buf, threadIdx.x);
    const float scale = 0.5f * 0.022097086912079608f;  // 0.5 / sqrt(2048)
    for (int k = threadIdx.x; k < 1024; k += 256) {
      float2 zk = buf[BIX(k)];
      float2 zn = buf[BIX((2048 - k) & 2047)];
      float f1r = zk.x + zn.x, f1i = zk.y - zn.y;
      float f2r = zk.y + zn.y, f2i = zk.x - zn.x;
      spec[(b * 128 + f0) * 1024 + k]     = sqrtf(f1r * f1r + f1i * f1i) * scale;
      spec[(b * 128 + f0 + 1) * 1024 + k] = sqrtf(f2r * f2r + f2i * f2i) * scale;
    }
  } else {
    int r = blk - 2048;           // 0..511
    int c = r >> 4;
    int g = r & 15;               // frames 2g (exp 2g+1), 2g+1 (exp 2g+2)
    float e1 = (float)(2 * g + 1);
    for (int k = threadIdx.x; k < 2048; k += 256) {
      int kk = (k <= 1024) ? k : 2048 - k;   // Hermitian (real) extension
      float cv = resin[c * 1025 + kk];
      cv = fminf(fmaxf(cv, 0.f), 0.9999f);
      float m1 = __powf(cv, e1);
      float m2 = m1 * cv;
      buf[BIX(__brev((unsigned)k) >> 21)] = make_float2(m1, m2);
    }
    __syncthreads();
    fft2048_stages(buf, threadIdx.x);
    for (int j = threadIdx.x; j < 2048; j += 256) {
      float h  = 0.5f - 0.5f * __cosf(0.0030679615757712823f * (float)j);
      float sc = h * (1.f / 2048.f);
      float2 z = buf[BIX(j)];
      frames[(c * 32 + 2 * g) * 2048 + j]     = z.x * sc;
      frames[(c * 32 + 2 * g + 1) * 2048 + j] = z.y * sc;
    }
  }
}

// ---------------- proj_in: h0[b,o,t] = sum_k Win[o][k]*spec[b,t,k] + bias ----------------
// v9 form (proven): float4 LDS reads (broadcast across half-wave), Win o-major,
// 8 frames per block (the Win amortization v12's fusion broke).
__global__ __launch_bounds__(256) void k_proj_in(const float* __restrict__ spec,
                                                 const float* __restrict__ Win,
                                                 const float* __restrict__ bias,
                                                 float* __restrict__ h0) {
  __shared__ float specL[8][1024];
  __shared__ float red[32][8][8];   // [o][tt][p]
  int b  = blockIdx.x >> 4;
  int t0 = (blockIdx.x & 15) * 8;
  for (int i = threadIdx.x; i < 8192; i += 256) {
    int tt = i >> 10, k = i & 1023;
    specL[tt][k] = spec[(b * 128 + t0 + tt) * 1024 + k];
  }
  __syncthreads();
  int o = threadIdx.x & 31, p = threadIdx.x >> 5;
  float part[8] = {0.f,0.f,0.f,0.f,0.f,0.f,0.f,0.f};
  const float4* Wrow = (const float4*)(Win + o * 1024);   // Win is [o][k]
  for (int k4 = p * 32; k4 < p * 32 + 32; ++k4) {         // 128 k per thread
    float4 w4 = Wrow[k4];
    int k = k4 * 4;
#pragma unroll
    for (int tt = 0; tt < 8; ++tt) {
      float4 s4 = *(const float4*)&specL[tt][k];
      part[tt] += w4.x * s4.x + w4.y * s4.y + w4.z * s4.z + w4.w * s4.w;
    }
  }
#pragma unroll
  for (int tt = 0; tt < 8; ++tt) red[o][tt][p] = part[tt];
  __syncthreads();
  int oo = threadIdx.x >> 3, tt2 = threadIdx.x & 7;
  float s = bias[oo];
#pragma unroll
  for (int p2 = 0; p2 < 8; ++p2) s += red[oo][tt2][p2];
  h0[b * 4096 + oo * 128 + t0 + tt2] = s;
}

// ---------------- chain (blocks 0..31) + fused overlap-add/B-pack (blocks 32..159) ----------------
__global__ __launch_bounds__(1024) void k_chain(const float* __restrict__ h0,
                                                const short* __restrict__ Whg,
                                                const short* __restrict__ Wlg,
                                                const float* __restrict__ bb,
                                                float* __restrict__ accout,
                                                const float* __restrict__ frames,
                                                short* __restrict__ Bh,
                                                short* __restrict__ Bl) {
  __shared__ __align__(16) short Hh[192 * 40];   // rows stride 40 bf16 (80 B)
  __shared__ __align__(16) short Hl[192 * 40];
  __shared__ float Hf[128 * 33];                 // fp32 H for exact residual
  __shared__ float bL[256];
  __shared__ float red[16];
  int blk = blockIdx.x, tid = threadIdx.x;

  if (blk >= 32) {                  // ---- obpack branch (no LDS use, no syncs) ----
    int ubb = (blk - 32) * 4 + (tid >> 8);   // old obpack block id 0..511
    int r   = tid & 255;
    int c   = ubb >> 4, o = ubb & 15;
    bf16x8 hv, lv;
#pragma unroll
    for (int j = 0; j < 8; ++j) {
      int fo = 8 * o + j;
      int g  = fo >> 2;
      int j0 = ((fo & 3) << 8) + r;
      float val = frames[(c * 32 + g) * 2048 + j0];
      if (g > 0) val += frames[(c * 32 + g - 1) * 2048 + j0 + 1024];
      unsigned bits = __float_as_uint(val);
      float rem = val - __uint_as_float(bits & 0xffff0000u);
      hv[j] = (short)(bits >> 16);
      lv[j] = (short)(__float_as_uint(rem) >> 16);
    }
    int unit = (ubb * 16 + (r >> 4)) * 16 + (r & 15);
    ((bf16x8*)Bh)[unit] = hv;
    ((bf16x8*)Bl)[unit] = lv;
    return;
  }

  int b = blk;
  for (int i = tid; i < 4096; i += 1024) {
    int t = i & 127;                 // h0 layout [o][t]
    int o = i >> 7;
    float val = h0[b * 4096 + i];
    Hf[t * 33 + o] = val;
    unsigned bits = __float_as_uint(val);
    float rem = val - __uint_as_float(bits & 0xffff0000u);
    Hh[t * 40 + o] = (short)(bits >> 16);
    Hl[t * 40 + o] = (short)(__float_as_uint(rem) >> 16);
  }
  for (int i = tid; i < 64 * 40; i += 1024) {    // zero pad rows 128..191
    Hh[128 * 40 + i] = 0;
    Hl[128 * 40 + i] = 0;
  }
  if (tid < 256) bL[tid] = bb[tid];
  __syncthreads();

  int wave = tid >> 6, lane = tid & 63;
  int quad = lane >> 4, l15 = lane & 15;
  int t0 = (wave & 7) * 16, o0 = (wave >> 3) * 16;
  int tD = t0 + quad * 4;          // D rows tD..tD+3
  int oD = o0 + l15;               // D col

  const bf16x8* Hh8 = (const bf16x8*)Hh;   // unit = row*5 + quad (40 bf16 = 5 units)
  const bf16x8* Hl8 = (const bf16x8*)Hl;
  const bf16x8* Wh8 = (const bf16x8*)Whg;  // unit = row*4 + quad (32 bf16 = 4 units)
  const bf16x8* Wl8 = (const bf16x8*)Wlg;

  float accsum[4] = {0.f, 0.f, 0.f, 0.f};
  const int DIL[8] = {1, 2, 4, 8, 16, 32, 64, 1};

#pragma unroll
  for (int s = 0; s < 8; ++s) {
    int arow = t0 + l15;
    int frow = arow + DIL[s];        // <= 191, pad rows give zeros
    bf16x8 Ah = Hh8[arow * 5 + quad];
    bf16x8 Al = Hl8[arow * 5 + quad];
    bf16x8 Fh = Hh8[frow * 5 + quad];
    bf16x8 Fl = Hl8[frow * 5 + quad];
    int w0row = ((s * 2 + 0) * 32 + oD) * 4 + quad;
    int w1row = ((s * 2 + 1) * 32 + oD) * 4 + quad;
    bf16x8 B0h = Wh8[w0row], B0l = Wl8[w0row];
    bf16x8 B1h = Wh8[w1row], B1l = Wl8[w1row];
    float bias = bL[s * 32 + oD];
    f32x4 acc = {bias, bias, bias, bias};
    MFMA16(acc, Ah, B0h); MFMA16(acc, Ah, B0l); MFMA16(acc, Al, B0h);
    MFMA16(acc, Fh, B1h); MFMA16(acc, Fh, B1l); MFMA16(acc, Fl, B1h);
    float hnew[4], lmax = 0.f;
#pragma unroll
    for (int r = 0; r < 4; ++r) {
      float sv = acc[r];
      sv = (sv > 0.f) ? sv : 0.2f * sv;       // leaky_relu 0.2
      sv += Hf[(tD + r) * 33 + oD];           // residual (exact fp32)
      hnew[r] = sv;
      lmax = fmaxf(lmax, fabsf(sv));
    }
#pragma unroll
    for (int off = 32; off > 0; off >>= 1)
      lmax = fmaxf(lmax, __shfl_down(lmax, off, 64));
    if (lane == 0) red[wave] = lmax;
    __syncthreads();                 // red visible; all H reads of this step done
    float mx = red[0];
#pragma unroll
    for (int i = 1; i < 16; ++i) mx = fmaxf(mx, red[i]);
    float nm = 1.f / (mx + 1e-8f);
#pragma unroll
    for (int r = 0; r < 4; ++r) {
      float hv = hnew[r] * nm;
      accsum[r] += hv;
      int t = tD + r;
      Hf[t * 33 + oD] = hv;
      unsigned bits = __float_as_uint(hv);
      float rem = hv - __uint_as_float(bits & 0xffff0000u);
      Hh[t * 40 + oD] = (short)(bits >> 16);
      Hl[t * 40 + oD] = (short)(__float_as_uint(rem) >> 16);
    }
    __syncthreads();                 // new H visible for next step
  }
#pragma unroll
  for (int r = 0; r < 4; ++r)
    accout[b * 4096 + (tD + r) * 32 + oD] = accsum[r];
}

// ---------------- sparse + dense, 8 t per block ----------------
__global__ __launch_bounds__(256) void k_sparse_dense(const float* __restrict__ acc,
                                                      const float* __restrict__ WsT,
                                                      const float* __restrict__ bs,
                                                      const float* __restrict__ WdT,
                                                      const float* __restrict__ bd,
                                                      float* __restrict__ out_sparse,
                                                      float* __restrict__ v) {
  __shared__ float accL[8][32];
  __shared__ float sL[8][256];
  __shared__ float red[8][8][32];   // [p][tt][c]
  int b = blockIdx.x >> 4, tq = blockIdx.x & 15;
  int t0 = tq * 8;
  int tid = threadIdx.x;
  accL[tid >> 5][tid & 31] = acc[b * 4096 + (t0 + (tid >> 5)) * 32 + (tid & 31)];
  __syncthreads();
  float bsv = bs[tid];
  float s[8];
#pragma unroll
  for (int j = 0; j < 8; ++j) s[j] = bsv;
  for (int m = 0; m < 32; ++m) {
    float w = WsT[m * 256 + tid];
#pragma unroll
    for (int j = 0; j < 8; ++j) s[j] += w * accL[j][m];
  }
  float* os = out_sparse + b * 32768 + tid * 128 + t0;
#pragma unroll
  for (int j = 0; j < 8; ++j) {
    s[j] = fmaxf(s[j], 0.f);
    os[j] = s[j];
    sL[j][tid] = s[j];
  }
  __syncthreads();
  int c = tid & 31, p = tid >> 5;
  float pp[8] = {0.f,0.f,0.f,0.f,0.f,0.f,0.f,0.f};
  for (int jj = 0; jj < 32; ++jj) {
    int o2 = p * 32 + jj;
    float w = WdT[o2 * 32 + c];
#pragma unroll
    for (int j = 0; j < 8; ++j) pp[j] += w * sL[j][o2];
  }
#pragma unroll
  for (int j = 0; j < 8; ++j) red[p][j][c] = pp[j];
  __syncthreads();
  {
    int tt = tid >> 5, cc = tid & 31;
    float vv = bd[cc];
#pragma unroll
    for (int p2i = 0; p2i < 8; ++p2i) vv += red[p2i][tt][cc];
    v[b * 4096 + cc * 128 + t0 + tt] = vv;
  }
}

// ---------------- final conv as MFMA GEMM, v11 (proven): two-phase + B prefetch ----------------
// v4 structure (two-phase, 40 KB LDS) + 1-step-ahead B prefetch across the
// flattened 16-step loop. VGPR ~104 -> 4 waves/SIMD cap (m69 boundary at 128);
// do NOT deepen prefetch (would cross 128-VGPR cliff and halve occupancy).
// XCD-group swizzle: all 32 b-blocks of one (j,uc) share one XCD's L2 slice.
__global__ __launch_bounds__(512, 4) void k_conv(const float* __restrict__ v,
                                                 const short* __restrict__ Bh,
                                                 const short* __restrict__ Bl,
                                                 float* __restrict__ y) {
  __shared__ __align__(16) short AH[32 * 264];   // [row 32][K 256 + pad 8]
  __shared__ __align__(16) short AL[32 * 264];
  __shared__ float vwin[2][16][48];              // [c-half][c_local][ii]

  // --- XCD-group swizzle: group e (20 of them) -> XCD e%8; batches fill slots.
  int xcd  = blockIdx.x & 7;
  int slot = blockIdx.x >> 3;
  int e, b;
  if      (slot < 32) { e = xcd;      b = slot; }
  else if (slot < 64) { e = xcd + 8;  b = slot - 32; }
  else                { e = (xcd < 4) ? (xcd + 16) : (xcd + 12);
                        b = (xcd < 4) ? (slot - 64) : (slot - 48); }
  int j, uc;
  if      (e < 2)  { j = 0; uc = e; }
  else if (e < 6)  { j = 1; uc = e - 2; }
  else if (e < 12) { j = 2; uc = e - 6; }
  else             { j = 3; uc = e - 12; }
  int D0 = 32 * j - 16 * uc;       // d = D0 - 15 + ii, ii in [0,46]

  // stage compact v windows (both c-halves): 2*16*47 floats
  for (int i = threadIdx.x; i < 1504; i += 512) {
    int ii = i % 47;
    int r  = i / 47;               // 0..31
    int c  = r & 15, ph = r >> 4;
    int d  = D0 - 15 + ii;
    vwin[ph][c][ii] = (d >= 0 && d < 128)
        ? v[b * 4096 + (16 * ph + c) * 128 + d] : 0.f;
  }
  __syncthreads();

  int lane = threadIdx.x & 63, wave = threadIdx.x >> 6;
  int quad = lane >> 4, l15 = lane & 15;
  int cq   = quad >> 1;            // low bit of c
  int og   = 2 * uc + (quad & 1);  // global u-octet
  int nt0  = wave * 2;             // 8 waves x 2 nt = 16 nt

  f32x4 acc00 = (f32x4)0.f, acc01 = (f32x4)0.f;   // [qs][t]
  f32x4 acc10 = (f32x4)0.f, acc11 = (f32x4)0.f;

  const bf16x8* AH8 = (const bf16x8*)AH;
  const bf16x8* AL8 = (const bf16x8*)AL;
  const bf16x8* Bh8 = (const bf16x8*)Bh;
  const bf16x8* Bl8 = (const bf16x8*)Bl;
  short2* AH2 = (short2*)AH;
  short2* AL2 = (short2*)AL;

  int abase0 = (0 * 16 + l15) * 33 + quad;   // bf16x8 units, row stride 33
  int abase1 = (1 * 16 + l15) * 33 + quad;

  // prefetch B for step 0 (p=0, ks=0 -> c = cq)
  bf16x8 pbh0, pbl0, pbh1, pbl1;
  {
    int bb0 = (cq * 16 + og) * 256 + l15;
    pbh0 = Bh8[bb0 + nt0 * 16];       pbl0 = Bl8[bb0 + nt0 * 16];
    pbh1 = Bh8[bb0 + (nt0 + 1) * 16]; pbl1 = Bl8[bb0 + (nt0 + 1) * 16];
  }

#pragma unroll
  for (int p = 0; p < 2; ++p) {
    // expand Toeplitz A (hi/lo split) for this c-half: 32 rows x 128 kk-pairs
    for (int i = threadIdx.x; i < 4096; i += 512) {
      int kk2 = i & 127;           // kk = 2*kk2 (pair shares c_local)
      int row = i >> 7;            // 0..31
      int cl  = kk2 >> 3;
      int uu  = (kk2 & 7) * 2;
      int ii  = row - uu + 15;
      float v0 = vwin[p][cl][ii];
      float v1 = vwin[p][cl][ii - 1];
      unsigned w0 = __float_as_uint(v0), w1 = __float_as_uint(v1);
      float r0 = v0 - __uint_as_float(w0 & 0xffff0000u);
      float r1 = v1 - __uint_as_float(w1 & 0xffff0000u);
      int u2 = row * 132 + kk2;    // short2 units, row stride 132
      AH2[u2] = make_short2((short)(w0 >> 16), (short)(w1 >> 16));
      AL2[u2] = make_short2((short)(__float_as_uint(r0) >> 16),
                            (short)(__float_as_uint(r1) >> 16));
    }
    __syncthreads();

#pragma unroll
    for (int ks = 0; ks < 8; ++ks) {
      // consume prefetched B for this step
      bf16x8 bh0 = pbh0, bl0 = pbl0, bh1 = pbh1, bl1 = pbl1;
      // issue prefetch for next step (crosses the phase barrier for p0->p1)
      int step = p * 8 + ks + 1;
      if (step < 16) {
        int cn  = 16 * (step >> 3) + 2 * (step & 7) + cq;
        int bbn = (cn * 16 + og) * 256 + l15;
        pbh0 = Bh8[bbn + nt0 * 16];       pbl0 = Bl8[bbn + nt0 * 16];
        pbh1 = Bh8[bbn + (nt0 + 1) * 16]; pbl1 = Bl8[bbn + (nt0 + 1) * 16];
      }
      bf16x8 ah0 = AH8[abase0 + ks * 4];
      bf16x8 al0 = AL8[abase0 + ks * 4];
      bf16x8 ah1 = AH8[abase1 + ks * 4];
      bf16x8 al1 = AL8[abase1 + ks * 4];
      MFMA16(acc00, ah0, bh0); MFMA16(acc00, ah0, bl0); MFMA16(acc00, al0, bh0);
      MFMA16(acc10, ah1, bh0); MFMA16(acc10, ah1, bl0); MFMA16(acc10, al1, bh0);
      MFMA16(acc01, ah0, bh1); MFMA16(acc01, ah0, bl1); MFMA16(acc01, al0, bh1);
      MFMA16(acc11, ah1, bh1); MFMA16(acc11, ah1, bl1); MFMA16(acc11, al1, bh1);
    }
    __syncthreads();               // A consumed; safe to overwrite in next phase
  }

  {
    float* yb0 = y + b * 32768 + (32 * j + 0 * 16 + quad * 4) * 256 + l15;
    float* yb1 = y + b * 32768 + (32 * j + 1 * 16 + quad * 4) * 256 + l15;
#pragma unroll
    for (int reg = 0; reg < 4; ++reg) {
      atomicAdd(yb0 + reg * 256 + (nt0 + 0) * 16, acc00[reg]);
      atomicAdd(yb0 + reg * 256 + (nt0 + 1) * 16, acc01[reg]);
      atomicAdd(yb1 + reg * 256 + (nt0 + 0) * 16, acc10[reg]);
      atomicAdd(yb1 + reg * 256 + (nt0 + 1) * 16, acc11[reg]);
    }
  }
}

extern "C" void kernel_launch(void* const* d_in, const int* in_sizes, int n_in,
                              void* d_out, int out_size, void* d_ws, size_t ws_size,
                              hipStream_t stream) {
  const float* audio = (const float*)d_in[0];
  const float* Win   = (const float*)d_in[1];
  const float* bin   = (const float*)d_in[2];
  const float* bw    = (const float*)d_in[3];
  const float* bb    = (const float*)d_in[4];
  const float* Ws    = (const float*)d_in[5];
  const float* bs    = (const float*)d_in[6];
  const float* Wd    = (const float*)d_in[7];
  const float* bd    = (const float*)d_in[8];
  const float* reson = (const float*)d_in[9];

  float* out = (float*)d_out;           // [0,1048576) = y ; [1048576,2097152) = sparse
  float* ws  = (float*)d_ws;

  float* spec   = ws + WS_SPEC;
  float* h0     = ws + WS_H0;
  float* accb   = ws + WS_ACC;
  float* vbuf   = ws + WS_V;
  float* WsT    = ws + WS_WST;
  float* WdT    = ws + WS_WDT;
  float* frames = ws + WS_FRAMES;
  // WS_RES region (dead after fusing overlap-add into chain launch) -> bf16 B packs
  short* Bh = (short*)(ws + WS_RES);               // 1,048,576 bf16 = 2 MB
  short* Bl = (short*)(ws + WS_RES + 524288u);     // 1,048,576 bf16 = 2 MB
  // chain-weight packs live in WS_V until k_sparse_dense overwrites it (after k_chain)
  short* Whg = (short*)(ws + WS_V);                // 16384 bf16 = 32 KB
  short* Wlg = (short*)(ws + WS_V + 8192u);        // 16384 bf16 = 32 KB

  // zero y region (atomicAdd target); d_out is poisoned before every launch
  hipMemsetAsync(d_out, 0, 1048576u * sizeof(float), stream);

  k_fft<<<2688, 256, 0, stream>>>(audio, reson, Win, Ws, Wd, bw,
                                  spec, frames, WsT, WdT, Whg, Wlg);
  k_proj_in<<<512, 256, 0, stream>>>(spec, Win, bin, h0);
  k_chain<<<160, 1024, 0, stream>>>(h0, Whg, Wlg, bb, accb, frames, Bh, Bl);
  k_sparse_dense<<<512, 256, 0, stream>>>(accb, WsT, bs, WdT, bd, out + 1048576, vbuf);
  k_conv<<<640, 512, 0, stream>>>(vbuf, Bh, Bl, out);
}